// Round 1
// baseline (3478.005 us; speedup 1.0000x reference)
//
#include <hip/hip_runtime.h>
#include <hip/hip_cooperative_groups.h>

namespace cg = cooperative_groups;

#define MDIM 1024
#define H4   4096
#define TKL  10
#define NT   30
#define NWFR 39                      // 30 + 10 - 1 wavefronts
#define GBLK 256
#define GTHR 1024
#define NWAVES (GBLK * (GTHR / 64))  // 4096 waves in grid

__device__ __forceinline__ float wred(float v) {
#pragma unroll
  for (int o = 32; o; o >>= 1) v += __shfl_xor(v, o, 64);
  return v;
}

// xcf[i][m] = mean over 12 t of x[c][s][t],  m = s*32 + c
__global__ void k_xcf(const float* __restrict__ x, float* __restrict__ xcf) {
  int idx = blockIdx.x * blockDim.x + threadIdx.x;
  if (idx >= NT * MDIM) return;
  int i = idx >> 10, m = idx & (MDIM - 1);
  int c = m & 31, s = m >> 5;
  const float* p = x + c * (32 * 360) + s * 360 + i * 12;
  float acc = 0.f;
#pragma unroll
  for (int k = 0; k < 12; ++k) acc += p[k];
  xcf[idx] = acc * (1.0f / 12.0f);
}

// S[i][m] = dot(weight[m,:], xcf[i,:]) + pe[i][m]   (one wave per output)
__global__ void k_s0(const float* __restrict__ xcf, const float* __restrict__ W,
                     float* __restrict__ S) {
  int wid = (blockIdx.x * blockDim.x + threadIdx.x) >> 6;
  int lane = threadIdx.x & 63;
  if (wid >= NT * MDIM) return;
  int i = wid >> 10, m = wid & (MDIM - 1);
  const float4* wr = (const float4*)(W + (size_t)m * MDIM);
  const float4* xr = (const float4*)(xcf + i * MDIM);
  float acc = 0.f;
#pragma unroll
  for (int k = 0; k < 4; ++k) {
    float4 w = wr[lane + (k << 6)];
    float4 xv = xr[lane + (k << 6)];
    acc += w.x * xv.x + w.y * xv.y + w.z * xv.z + w.w * xv.w;
  }
  acc = wred(acc);
  if (lane == 0) {
    int e = m & ~1;  // even base index used in the exponent
    float ang = (float)i / powf(10000.0f, (float)e / 512.0f);
    float pe = (m & 1) ? cosf(ang) : sinf(ang);
    S[wid] = acc + pe;
  }
}

// Cooperative main loop over 39 wavefronts; 2 grid syncs per wavefront.
// State S lives in d_out (30x1024). ocum[a] = Wo[a] @ vcum[a], kept incrementally.
__global__ __launch_bounds__(GTHR) void k_main(
    const float* __restrict__ Wv, const float* __restrict__ Wo,
    const float* __restrict__ fc1w, const float* __restrict__ fc1b,
    const float* __restrict__ fc2w, const float* __restrict__ fc2b,
    const float* __restrict__ lng, const float* __restrict__ lnb,
    const float* __restrict__ lzg, const float* __restrict__ lzb,
    float* __restrict__ S, float* __restrict__ ocum,
    float* __restrict__ vbuf, float* __restrict__ hbuf) {
  cg::grid_group grid = cg::this_grid();
  __shared__ __align__(16) float lds[25600];  // A: z/x2 [10][2][1024]; B: v[5][1024]+h[5][4096]
  __shared__ float4 stats[TKL];
  __shared__ float part[4][4][5];             // fc2 partials [row_local][kq][cell]

  const int tid = threadIdx.x;
  const int lane = tid & 63;
  const int bwave = tid >> 6;                       // 0..15
  const int gw = blockIdx.x * (GTHR / 64) + bwave;  // global wave id

  for (int t = 0; t < NWFR; ++t) {
    const int alo = (t - (NT - 1)) > 0 ? (t - (NT - 1)) : 0;
    const int ahi = t < (TKL - 1) ? t : (TKL - 1);
    const int nc = ahi - alo + 1;  // active cells, <= 10

    // ---- LN stats: one wave per cell (two-pass, matches reference) ----
    if (bwave < nc) {
      const int a = alo + bwave, i = t - a;
      const float* sp = S + i * MDIM;
      const float* op = ocum + a * MDIM;
      float sv[16], tv[16];
#pragma unroll
      for (int k = 0; k < 16; ++k) {
        sv[k] = sp[lane + (k << 6)];
        tv[k] = sv[k] + op[lane + (k << 6)];
      }
      float s1 = 0.f, t1 = 0.f;
#pragma unroll
      for (int k = 0; k < 16; ++k) { s1 += sv[k]; t1 += tv[k]; }
      const float mu_s = wred(s1) * (1.0f / MDIM);
      const float mu_t = wred(t1) * (1.0f / MDIM);
      float s2 = 0.f, t2 = 0.f;
#pragma unroll
      for (int k = 0; k < 16; ++k) {
        float d = sv[k] - mu_s; s2 += d * d;
        float e = tv[k] - mu_t; t2 += e * e;
      }
      const float var_s = wred(s2) * (1.0f / MDIM);
      const float var_t = wred(t2) * (1.0f / MDIM);
      if (lane == 0)
        stats[bwave] = make_float4(mu_s, rsqrtf(var_s + 1e-5f),
                                   mu_t, rsqrtf(var_t + 1e-5f));
    }
    __syncthreads();

    // ---- elementwise: z = LN1(s), x2 = LN2(s+ocum) + (s+ocum) into LDS ----
    {
      const float g1 = lng[tid], b1 = lnb[tid], g2 = lzg[tid], b2 = lzb[tid];
#pragma unroll
      for (int c = 0; c < TKL; ++c)
        if (c < nc) {
          const int a = alo + c, i = t - a;
          const float4 st = stats[c];
          const float sv = S[i * MDIM + tid];
          const float tv = sv + ocum[a * MDIM + tid];
          lds[c * 2048 + tid] = (sv - st.x) * st.y * g1 + b1;
          lds[c * 2048 + MDIM + tid] = (tv - st.z) * st.w * g2 + b2 + tv;
        }
    }
    __syncthreads();

    // ---- Phase A jobs ----
    // v = Wv[a] @ z   (skipped for i==29: never consumed)
    for (int j = gw; j < nc * MDIM; j += NWAVES) {
      const int ci = j >> 10, row = j & (MDIM - 1);
      const int a = alo + ci, i = t - a;
      if (i == NT - 1) continue;
      const float4* wr = (const float4*)(Wv + ((size_t)a << 20) + ((size_t)row << 10));
      const float4* zz = (const float4*)(lds + ci * 2048);
      float acc = 0.f;
#pragma unroll
      for (int k = 0; k < 4; ++k) {
        float4 w = wr[lane + (k << 6)];
        float4 z = zz[lane + (k << 6)];
        acc += w.x * z.x + w.y * z.y + w.z * z.z + w.w * z.w;
      }
      acc = wred(acc);
      if (lane == 0) vbuf[a * MDIM + row] = acc;
    }
    // h = gelu(fc1 @ x2 + b): one row per wave, weight row reused across all cells
    for (int j = gw; j < H4; j += NWAVES) {
      const float4* wr = (const float4*)(fc1w + (size_t)j * MDIM);
      float acc[TKL];
#pragma unroll
      for (int c = 0; c < TKL; ++c) acc[c] = 0.f;
#pragma unroll
      for (int k = 0; k < 4; ++k) {
        const float4 w = wr[lane + (k << 6)];
#pragma unroll
        for (int c = 0; c < TKL; ++c)
          if (c < nc) {
            const float4* x4 = (const float4*)(lds + c * 2048 + MDIM);
            const float4 xv = x4[lane + (k << 6)];
            acc[c] += w.x * xv.x + w.y * xv.y + w.z * xv.z + w.w * xv.w;
          }
      }
#pragma unroll
      for (int c = 0; c < TKL; ++c)
        if (c < nc) {
          float v = wred(acc[c]);
          if (lane == 0) {
            const float xg = v + fc1b[j];
            hbuf[(alo + c) * H4 + j] =
                0.5f * xg * (1.0f + erff(xg * 0.70710678118654752f));
          }
        }
    }
    grid.sync();

    // ---- Phase B: s' = fc2 @ h + b ; ocum[a] += Wo[a] @ v ----
    for (int chunk = 0; chunk < 2; ++chunk) {
      const int c0 = chunk * 5;
      const int nch = (nc - c0) < 5 ? (nc - c0) : 5;
      if (nch <= 0) break;  // uniform across grid
      __syncthreads();      // LDS reuse guard
      for (int c = 0; c < nch; ++c) {
        const int a = alo + c0 + c;
        lds[c * MDIM + tid] = vbuf[a * MDIM + tid];
#pragma unroll
        for (int q = 0; q < 4; ++q)
          lds[5 * MDIM + c * H4 + q * GTHR + tid] = hbuf[a * H4 + q * GTHR + tid];
      }
      __syncthreads();
      // fc2: 4 rows per block, each row split over 4 waves (k-quarters)
      {
        const int rl = bwave & 3;
        const int kq = bwave >> 2;
        const int j = (blockIdx.x << 2) | rl;
        const float4* wr = (const float4*)(fc2w + (size_t)j * H4) + (kq << 8);
        float acc[5];
#pragma unroll
        for (int c = 0; c < 5; ++c) acc[c] = 0.f;
#pragma unroll
        for (int k = 0; k < 4; ++k) {
          const float4 w = wr[lane + (k << 6)];
#pragma unroll
          for (int c = 0; c < 5; ++c)
            if (c < nch) {
              const float4* h4 = (const float4*)(lds + 5 * MDIM + c * H4) + (kq << 8);
              const float4 hh = h4[lane + (k << 6)];
              acc[c] += w.x * hh.x + w.y * hh.y + w.z * hh.z + w.w * hh.w;
            }
        }
#pragma unroll
        for (int c = 0; c < 5; ++c)
          if (c < nch) {
            float v = wred(acc[c]);
            if (lane == 0) part[rl][kq][c] = v;
          }
      }
      __syncthreads();
      if (tid < 20) {
        const int rl = tid & 3, c = tid >> 2;
        if (c < nch) {
          const int j = (blockIdx.x << 2) | rl;
          const int a = alo + c0 + c, i = t - a;
          S[i * MDIM + j] = part[rl][0][c] + part[rl][1][c] + part[rl][2][c] +
                            part[rl][3][c] + fc2b[j];
        }
      }
      // ocum[a] += Wo[a] @ v   (skip i==29: never consumed)
      for (int jj = gw; jj < nch * MDIM; jj += NWAVES) {
        const int c = jj >> 10, row = jj & (MDIM - 1);
        const int a = alo + c0 + c, i = t - a;
        if (i == NT - 1) continue;
        const float4* wr = (const float4*)(Wo + ((size_t)a << 20) + ((size_t)row << 10));
        const float4* vv = (const float4*)(lds + c * MDIM);
        float acc = 0.f;
#pragma unroll
        for (int k = 0; k < 4; ++k) {
          float4 w = wr[lane + (k << 6)];
          float4 x = vv[lane + (k << 6)];
          acc += w.x * x.x + w.y * x.y + w.z * x.z + w.w * x.w;
        }
        acc = wred(acc);
        if (lane == 0) ocum[a * MDIM + row] += acc;
      }
    }
    grid.sync();
  }
}

extern "C" void kernel_launch(void* const* d_in, const int* in_sizes, int n_in,
                              void* d_out, int out_size, void* d_ws, size_t ws_size,
                              hipStream_t stream) {
  const float* x    = (const float*)d_in[0];
  const float* W    = (const float*)d_in[1];
  // d_in[2] = Wq, d_in[3] = Wk: dead (softmax of a scalar == 1)
  const float* Wv   = (const float*)d_in[4];
  const float* Wo   = (const float*)d_in[5];
  const float* lng  = (const float*)d_in[6];
  const float* lnb  = (const float*)d_in[7];
  const float* lzg  = (const float*)d_in[8];
  const float* lzb  = (const float*)d_in[9];
  const float* fc1w = (const float*)d_in[10];
  const float* fc1b = (const float*)d_in[11];
  const float* fc2w = (const float*)d_in[12];
  const float* fc2b = (const float*)d_in[13];
  float* S = (float*)d_out;  // state buffer doubles as output (30x1024)

  float* xcf  = (float*)d_ws;        // 30*1024
  float* ocum = xcf + NT * MDIM;     // 10*1024
  float* vbuf = ocum + TKL * MDIM;   // 10*1024
  float* hbuf = vbuf + TKL * MDIM;   // 10*4096

  hipLaunchKernelGGL(k_xcf, dim3((NT * MDIM + 255) / 256), dim3(256), 0, stream, x, xcf);
  hipLaunchKernelGGL(k_s0, dim3(NT * MDIM / 4), dim3(256), 0, stream, xcf, W, S);
  hipMemsetAsync(ocum, 0, TKL * MDIM * sizeof(float), stream);

  void* args[] = {(void*)&Wv,  (void*)&Wo,  (void*)&fc1w, (void*)&fc1b,
                  (void*)&fc2w, (void*)&fc2b, (void*)&lng, (void*)&lnb,
                  (void*)&lzg, (void*)&lzb, (void*)&S,   (void*)&ocum,
                  (void*)&vbuf, (void*)&hbuf};
  hipLaunchCooperativeKernel((void*)k_main, dim3(GBLK), dim3(GTHR), args, 0, stream);
}

// Round 2
// 2067.904 us; speedup vs baseline: 1.6819x; 1.6819x over previous
//
#include <hip/hip_runtime.h>

#define MDIM 1024
#define H4   4096
#define TKL  10
#define NT   30
#define NWFR 39
#define GBLK 256
#define GTHR 1024
#define NWAVES (GBLK * (GTHR / 64))

#define AGENT __HIP_MEMORY_SCOPE_AGENT

__device__ __forceinline__ float gld(const float* p) {
  return __hip_atomic_load(p, __ATOMIC_RELAXED, AGENT);
}
__device__ __forceinline__ void gst(float* p, float v) {
  __hip_atomic_store(p, v, __ATOMIC_RELAXED, AGENT);
}
__device__ __forceinline__ float b2f(unsigned u) {  // low 16 bits = bf16
  return __uint_as_float(u << 16);
}
__device__ __forceinline__ unsigned short f2b(float f) {  // RNE
  unsigned u = __float_as_uint(f);
  u += 0x7fffu + ((u >> 16) & 1u);
  return (unsigned short)(u >> 16);
}
__device__ __forceinline__ float wred(float v) {
#pragma unroll
  for (int o = 32; o; o >>= 1) v += __shfl_xor(v, o, 64);
  return v;
}

// ---- prologue: f32 -> bf16 (packed), 8 elems/thread ----
__global__ void k_cvt(const float* __restrict__ in, unsigned short* __restrict__ out, int n8) {
  int g = blockIdx.x * blockDim.x + threadIdx.x;
  if (g >= n8) return;
  const float4* p = (const float4*)in;
  float4 a = p[2 * g], b = p[2 * g + 1];
  uint4 o;
  o.x = (unsigned)f2b(a.x) | ((unsigned)f2b(a.y) << 16);
  o.y = (unsigned)f2b(a.z) | ((unsigned)f2b(a.w) << 16);
  o.z = (unsigned)f2b(b.x) | ((unsigned)f2b(b.y) << 16);
  o.w = (unsigned)f2b(b.z) | ((unsigned)f2b(b.w) << 16);
  ((uint4*)out)[g] = o;
}

__global__ void k_xcf(const float* __restrict__ x, float* __restrict__ xcf) {
  int idx = blockIdx.x * blockDim.x + threadIdx.x;
  if (idx >= NT * MDIM) return;
  int i = idx >> 10, m = idx & (MDIM - 1);
  int c = m & 31, s = m >> 5;
  const float* p = x + c * (32 * 360) + s * 360 + i * 12;
  float acc = 0.f;
#pragma unroll
  for (int k = 0; k < 12; ++k) acc += p[k];
  xcf[idx] = acc * (1.0f / 12.0f);
}

__global__ void k_s0(const float* __restrict__ xcf, const float* __restrict__ W,
                     float* __restrict__ S) {
  int wid = (blockIdx.x * blockDim.x + threadIdx.x) >> 6;
  int lane = threadIdx.x & 63;
  if (wid >= NT * MDIM) return;
  int i = wid >> 10, m = wid & (MDIM - 1);
  const float4* wr = (const float4*)(W + (size_t)m * MDIM);
  const float4* xr = (const float4*)(xcf + i * MDIM);
  float acc = 0.f;
#pragma unroll
  for (int k = 0; k < 4; ++k) {
    float4 w = wr[lane + (k << 6)];
    float4 xv = xr[lane + (k << 6)];
    acc += w.x * xv.x + w.y * xv.y + w.z * xv.z + w.w * xv.w;
  }
  acc = wred(acc);
  if (lane == 0) {
    int e = m & ~1;
    float ang = (float)i / powf(10000.0f, (float)e / 512.0f);
    float pe = (m & 1) ? cosf(ang) : sinf(ang);
    S[wid] = acc + pe;
  }
}

// fence-free grid barrier: data moves via agent-scope relaxed atomics (L2-bypass)
__device__ __forceinline__ void gbarrier(unsigned* bar, unsigned target) {
  __syncthreads();  // drains each wave's vmcnt before s_barrier
  if (threadIdx.x == 0) {
    __hip_atomic_fetch_add(bar, 1u, __ATOMIC_RELAXED, AGENT);
    while (__hip_atomic_load(bar, __ATOMIC_RELAXED, AGENT) < target)
      __builtin_amdgcn_s_sleep(2);
  }
  __syncthreads();
}

__global__ __launch_bounds__(GTHR) void k_main(
    const unsigned short* __restrict__ Wvh, const unsigned short* __restrict__ Woh,
    const unsigned short* __restrict__ fc1h, const float* __restrict__ fc1b,
    const unsigned short* __restrict__ fc2h, const float* __restrict__ fc2b,
    const float* __restrict__ lng, const float* __restrict__ lnb,
    const float* __restrict__ lzg, const float* __restrict__ lzb,
    float* __restrict__ S, float* __restrict__ ocum,
    float* __restrict__ vbuf, float* __restrict__ hbuf, unsigned* __restrict__ bar) {
  __shared__ __align__(16) float lds[25600];  // A: z/x2 [10][2][1024]; B: v[5][1024]+h[5][4096]
  __shared__ float4 stats[TKL];
  __shared__ float part[4][4][5];

  const int tid = threadIdx.x;
  const int lane = tid & 63;
  const int bwave = tid >> 6;
  const int gw = blockIdx.x * (GTHR / 64) + bwave;
  const float g1 = lng[tid], b1 = lnb[tid], g2 = lzg[tid], b2 = lzb[tid];
  unsigned tgt = 0;

  for (int t = 0; t < NWFR; ++t) {
    const int alo = (t - (NT - 1)) > 0 ? (t - (NT - 1)) : 0;
    const int ahi = t < (TKL - 1) ? t : (TKL - 1);
    const int nc = ahi - alo + 1;

    // ---- LN stats: one wave per cell ----
    if (bwave < nc) {
      const int a = alo + bwave, i = t - a;
      const float* sp = S + i * MDIM;
      const float* op = ocum + a * MDIM;
      float sv[16], tv[16];
#pragma unroll
      for (int k = 0; k < 16; ++k) {
        sv[k] = gld(sp + lane + (k << 6));
        tv[k] = sv[k] + gld(op + lane + (k << 6));
      }
      float s1 = 0.f, t1 = 0.f;
#pragma unroll
      for (int k = 0; k < 16; ++k) { s1 += sv[k]; t1 += tv[k]; }
      const float mu_s = wred(s1) * (1.0f / MDIM);
      const float mu_t = wred(t1) * (1.0f / MDIM);
      float s2 = 0.f, t2 = 0.f;
#pragma unroll
      for (int k = 0; k < 16; ++k) {
        float d = sv[k] - mu_s; s2 += d * d;
        float e = tv[k] - mu_t; t2 += e * e;
      }
      const float var_s = wred(s2) * (1.0f / MDIM);
      const float var_t = wred(t2) * (1.0f / MDIM);
      if (lane == 0)
        stats[bwave] = make_float4(mu_s, rsqrtf(var_s + 1e-5f),
                                   mu_t, rsqrtf(var_t + 1e-5f));
    }
    __syncthreads();

    // ---- elementwise: z, x2 into LDS (f32) ----
#pragma unroll
    for (int c = 0; c < TKL; ++c)
      if (c < nc) {
        const int a = alo + c, i = t - a;
        const float4 st = stats[c];
        const float sv = gld(S + i * MDIM + tid);
        const float tv = sv + gld(ocum + a * MDIM + tid);
        lds[c * 2048 + tid] = (sv - st.x) * st.y * g1 + b1;
        lds[c * 2048 + MDIM + tid] = (tv - st.z) * st.w * g2 + b2 + tv;
      }
    __syncthreads();

    // ---- Phase A: v = Wv@z (2 rows/job), h = gelu(fc1@x2) (1 row/wave, all cells) ----
    for (int j = gw; j < nc * 512; j += NWAVES) {
      const int ci = j >> 9;
      const int a = alo + ci, i = t - a;
      if (i == NT - 1) continue;
      const int row0 = (j & 511) << 1;
      const uint2* w2 = (const uint2*)(Wvh + ((size_t)a << 20) + ((size_t)row0 << 10));
      const float4* z4 = (const float4*)(lds + ci * 2048);
      float a0 = 0.f, a1 = 0.f;
#pragma unroll
      for (int k = 0; k < 4; ++k) {
        const int g = lane + (k << 6);
        const uint2 wa = w2[g], wb = w2[256 + g];
        const float4 z = z4[g];
        a0 += b2f(wa.x & 0xffff) * z.x + b2f(wa.x >> 16) * z.y +
              b2f(wa.y & 0xffff) * z.z + b2f(wa.y >> 16) * z.w;
        a1 += b2f(wb.x & 0xffff) * z.x + b2f(wb.x >> 16) * z.y +
              b2f(wb.y & 0xffff) * z.z + b2f(wb.y >> 16) * z.w;
      }
      a0 = wred(a0); a1 = wred(a1);
      if (lane == 0) {
        gst(vbuf + a * MDIM + row0, a0);
        gst(vbuf + a * MDIM + row0 + 1, a1);
      }
    }
    for (int j = gw; j < H4; j += NWAVES) {
      const uint2* w2 = (const uint2*)(fc1h + ((size_t)j << 10));
      float wf[16];
#pragma unroll
      for (int k = 0; k < 4; ++k) {
        const uint2 w = w2[lane + (k << 6)];
        wf[4 * k] = b2f(w.x & 0xffff); wf[4 * k + 1] = b2f(w.x >> 16);
        wf[4 * k + 2] = b2f(w.y & 0xffff); wf[4 * k + 3] = b2f(w.y >> 16);
      }
      const float bias = fc1b[j];
#pragma unroll
      for (int c = 0; c < TKL; ++c)
        if (c < nc) {
          const float4* x4 = (const float4*)(lds + c * 2048 + MDIM);
          float acc = 0.f;
#pragma unroll
          for (int k = 0; k < 4; ++k) {
            const float4 x = x4[lane + (k << 6)];
            acc += wf[4 * k] * x.x + wf[4 * k + 1] * x.y +
                   wf[4 * k + 2] * x.z + wf[4 * k + 3] * x.w;
          }
          acc = wred(acc);
          if (lane == 0) {
            const float xg = acc + bias;
            gst(hbuf + (alo + c) * H4 + j,
                0.5f * xg * (1.0f + erff(xg * 0.70710678118654752f)));
          }
        }
    }
    tgt += GBLK; gbarrier(bar, tgt);

    // ---- Phase B (2 chunks of <=5 cells): fc2 + Wo/ocum ----
    for (int chunk = 0; chunk < 2; ++chunk) {
      const int c0 = chunk * 5;
      const int nch = (nc - c0) < 5 ? (nc - c0) : 5;
      if (nch <= 0) break;  // uniform
      __syncthreads();
      for (int c = 0; c < nch; ++c) {
        const int a = alo + c0 + c;
        lds[c * MDIM + tid] = gld(vbuf + a * MDIM + tid);
#pragma unroll
        for (int q = 0; q < 4; ++q)
          lds[5 * MDIM + c * H4 + q * MDIM + tid] = gld(hbuf + a * H4 + q * MDIM + tid);
      }
      __syncthreads();
      {  // fc2: 4 rows/block x 4 k-quarters
        const int rl = bwave & 3, kq = bwave >> 2;
        const int jrow = (blockIdx.x << 2) | rl;
        const uint2* w2 = (const uint2*)(fc2h + ((size_t)jrow << 12)) + (kq << 8);
        float wf[16];
#pragma unroll
        for (int k = 0; k < 4; ++k) {
          const uint2 w = w2[lane + (k << 6)];
          wf[4 * k] = b2f(w.x & 0xffff); wf[4 * k + 1] = b2f(w.x >> 16);
          wf[4 * k + 2] = b2f(w.y & 0xffff); wf[4 * k + 3] = b2f(w.y >> 16);
        }
#pragma unroll
        for (int c = 0; c < 5; ++c)
          if (c < nch) {
            const float4* h4 = (const float4*)(lds + 5 * MDIM + c * H4 + kq * MDIM);
            float acc = 0.f;
#pragma unroll
            for (int k = 0; k < 4; ++k) {
              const float4 h = h4[lane + (k << 6)];
              acc += wf[4 * k] * h.x + wf[4 * k + 1] * h.y +
                     wf[4 * k + 2] * h.z + wf[4 * k + 3] * h.w;
            }
            acc = wred(acc);
            if (lane == 0) part[rl][kq][c] = acc;
          }
      }
      __syncthreads();
      if (tid < 20) {
        const int rl = tid & 3, c = tid >> 2;
        if (c < nch) {
          const int jrow = (blockIdx.x << 2) | rl;
          const int a = alo + c0 + c, i = t - a;
          gst(S + i * MDIM + jrow, part[rl][0][c] + part[rl][1][c] +
                                       part[rl][2][c] + part[rl][3][c] + fc2b[jrow]);
        }
      }
      for (int j = gw; j < nch * 512; j += NWAVES) {
        const int ci = j >> 9;
        const int a = alo + c0 + ci, i = t - a;
        if (i == NT - 1) continue;
        const int row0 = (j & 511) << 1;
        const uint2* w2 = (const uint2*)(Woh + ((size_t)a << 20) + ((size_t)row0 << 10));
        const float4* v4 = (const float4*)(lds + ci * MDIM);
        float a0 = 0.f, a1 = 0.f;
#pragma unroll
        for (int k = 0; k < 4; ++k) {
          const int g = lane + (k << 6);
          const uint2 wa = w2[g], wb = w2[256 + g];
          const float4 v = v4[g];
          a0 += b2f(wa.x & 0xffff) * v.x + b2f(wa.x >> 16) * v.y +
                b2f(wa.y & 0xffff) * v.z + b2f(wa.y >> 16) * v.w;
          a1 += b2f(wb.x & 0xffff) * v.x + b2f(wb.x >> 16) * v.y +
                b2f(wb.y & 0xffff) * v.z + b2f(wb.y >> 16) * v.w;
        }
        a0 = wred(a0); a1 = wred(a1);
        if (lane == 0) {
          float* p0 = ocum + a * MDIM + row0;
          gst(p0, gld(p0) + a0);
          gst(p0 + 1, gld(p0 + 1) + a1);
        }
      }
    }
    tgt += GBLK; gbarrier(bar, tgt);
  }
}

extern "C" void kernel_launch(void* const* d_in, const int* in_sizes, int n_in,
                              void* d_out, int out_size, void* d_ws, size_t ws_size,
                              hipStream_t stream) {
  const float* x    = (const float*)d_in[0];
  const float* W    = (const float*)d_in[1];
  const float* Wv   = (const float*)d_in[4];
  const float* Wo   = (const float*)d_in[5];
  const float* lng  = (const float*)d_in[6];
  const float* lnb  = (const float*)d_in[7];
  const float* lzg  = (const float*)d_in[8];
  const float* lzb  = (const float*)d_in[9];
  const float* fc1w = (const float*)d_in[10];
  const float* fc1b = (const float*)d_in[11];
  const float* fc2w = (const float*)d_in[12];
  const float* fc2b = (const float*)d_in[13];
  float* S = (float*)d_out;

  float* xcf  = (float*)d_ws;            // 30720 f32
  float* ocum = xcf + 30720;             // 10240
  float* vbuf = ocum + 10240;            // 10240
  float* hbuf = vbuf + 10240;            // 40960
  unsigned* bar = (unsigned*)(hbuf + 40960);  // 64 f32 slot
  unsigned short* Wvh  = (unsigned short*)(hbuf + 40960 + 64);
  unsigned short* Woh  = Wvh + (size_t)TKL * MDIM * MDIM;
  unsigned short* fc1h = Woh + (size_t)TKL * MDIM * MDIM;
  unsigned short* fc2h = fc1h + (size_t)H4 * MDIM;

  hipLaunchKernelGGL(k_cvt, dim3((TKL * MDIM * MDIM / 8 + 255) / 256), dim3(256), 0, stream,
                     Wv, Wvh, TKL * MDIM * MDIM / 8);
  hipLaunchKernelGGL(k_cvt, dim3((TKL * MDIM * MDIM / 8 + 255) / 256), dim3(256), 0, stream,
                     Wo, Woh, TKL * MDIM * MDIM / 8);
  hipLaunchKernelGGL(k_cvt, dim3((H4 * MDIM / 8 + 255) / 256), dim3(256), 0, stream,
                     fc1w, fc1h, H4 * MDIM / 8);
  hipLaunchKernelGGL(k_cvt, dim3((H4 * MDIM / 8 + 255) / 256), dim3(256), 0, stream,
                     fc2w, fc2h, H4 * MDIM / 8);
  hipLaunchKernelGGL(k_xcf, dim3((NT * MDIM + 255) / 256), dim3(256), 0, stream, x, xcf);
  hipLaunchKernelGGL(k_s0, dim3(NT * MDIM / 4), dim3(256), 0, stream, xcf, W, S);
  hipMemsetAsync(ocum, 0, TKL * MDIM * sizeof(float), stream);
  hipMemsetAsync(bar, 0, sizeof(unsigned), stream);

  void* args[] = {(void*)&Wvh, (void*)&Woh, (void*)&fc1h, (void*)&fc1b,
                  (void*)&fc2h, (void*)&fc2b, (void*)&lng, (void*)&lnb,
                  (void*)&lzg, (void*)&lzb, (void*)&S,   (void*)&ocum,
                  (void*)&vbuf, (void*)&hbuf, (void*)&bar};
  hipLaunchCooperativeKernel((void*)k_main, dim3(GBLK), dim3(GTHR), args, 0, stream);
}

// Round 4
// 1421.468 us; speedup vs baseline: 2.4468x; 1.4548x over previous
//
#include <hip/hip_runtime.h>

#define MDIM 1024
#define H4   4096
#define TKL  10
#define NT   30
#define NWFR 39
#define GBLK 256
#define GTHR 1024
#define NWAVES 4096
#define AGENT __HIP_MEMORY_SCOPE_AGENT

typedef unsigned long long ull;

__device__ __forceinline__ float gld(const float* p) {
  return __hip_atomic_load(p, __ATOMIC_RELAXED, AGENT);
}
__device__ __forceinline__ void gst(float* p, float v) {
  __hip_atomic_store(p, v, __ATOMIC_RELAXED, AGENT);
}
__device__ __forceinline__ ull gld8(const void* p) {
  return __hip_atomic_load((const ull*)p, __ATOMIC_RELAXED, AGENT);
}
__device__ __forceinline__ void gst8(float* p, ull v) {
  __hip_atomic_store((ull*)p, v, __ATOMIC_RELAXED, AGENT);
}
__device__ __forceinline__ float b2f(unsigned u) { return __uint_as_float(u << 16); }
__device__ __forceinline__ unsigned short f2b(float f) {  // RNE
  unsigned u = __float_as_uint(f);
  u += 0x7fffu + ((u >> 16) & 1u);
  return (unsigned short)(u >> 16);
}
__device__ __forceinline__ float wred(float v) {
#pragma unroll
  for (int o = 32; o; o >>= 1) v += __shfl_xor(v, o, 64);
  return v;
}
__device__ __forceinline__ float dot8u(uint2 w, uint2 h, float acc) {
  acc += b2f(w.x & 0xffff) * b2f(h.x & 0xffff) + b2f(w.x >> 16) * b2f(h.x >> 16);
  acc += b2f(w.y & 0xffff) * b2f(h.y & 0xffff) + b2f(w.y >> 16) * b2f(h.y >> 16);
  return acc;
}

__global__ void k_cvt(const float* __restrict__ in, unsigned short* __restrict__ out, int n8) {
  int g = blockIdx.x * blockDim.x + threadIdx.x;
  if (g >= n8) return;
  const float4* p = (const float4*)in;
  float4 a = p[2 * g], b = p[2 * g + 1];
  uint4 o;
  o.x = (unsigned)f2b(a.x) | ((unsigned)f2b(a.y) << 16);
  o.y = (unsigned)f2b(a.z) | ((unsigned)f2b(a.w) << 16);
  o.z = (unsigned)f2b(b.x) | ((unsigned)f2b(b.y) << 16);
  o.w = (unsigned)f2b(b.z) | ((unsigned)f2b(b.w) << 16);
  ((uint4*)out)[g] = o;
}

__global__ void k_xcf(const float* __restrict__ x, float* __restrict__ xcf) {
  int idx = blockIdx.x * blockDim.x + threadIdx.x;
  if (idx >= NT * MDIM) return;
  int i = idx >> 10, m = idx & (MDIM - 1);
  int c = m & 31, s = m >> 5;
  const float* p = x + c * (32 * 360) + s * 360 + i * 12;
  float acc = 0.f;
#pragma unroll
  for (int k = 0; k < 12; ++k) acc += p[k];
  xcf[idx] = acc * (1.0f / 12.0f);
}

__global__ void k_s0(const float* __restrict__ xcf, const float* __restrict__ W,
                     float* __restrict__ S) {
  int wid = (blockIdx.x * blockDim.x + threadIdx.x) >> 6;
  int lane = threadIdx.x & 63;
  if (wid >= NT * MDIM) return;
  int i = wid >> 10, m = wid & (MDIM - 1);
  const float4* wr = (const float4*)(W + (size_t)m * MDIM);
  const float4* xr = (const float4*)(xcf + i * MDIM);
  float acc = 0.f;
#pragma unroll
  for (int k = 0; k < 4; ++k) {
    float4 w = wr[lane + (k << 6)];
    float4 xv = xr[lane + (k << 6)];
    acc += w.x * xv.x + w.y * xv.y + w.z * xv.z + w.w * xv.w;
  }
  acc = wred(acc);
  if (lane == 0) {
    int e = m & ~1;
    float ang = (float)i / powf(10000.0f, (float)e / 512.0f);
    float pe = (m & 1) ? cosf(ang) : sinf(ang);
    S[wid] = acc + pe;
  }
}

// two-level fence-free barrier: 8 leaf counters + root + go flag, monotone epochs
__device__ __forceinline__ void gbar(unsigned* bar, unsigned ep) {
  asm volatile("s_waitcnt vmcnt(0)" ::: "memory");  // drain this wave's far stores
  __syncthreads();
  if (threadIdx.x == 0) {
    unsigned* leaf = bar + ((blockIdx.x & 7) << 5);
    const unsigned prev = __hip_atomic_fetch_add(leaf, 1u, __ATOMIC_RELAXED, AGENT);
    if (prev == ep * 32u - 1u) {  // last of this leaf's 32 blocks
      const unsigned r = __hip_atomic_fetch_add(bar + 256, 1u, __ATOMIC_RELAXED, AGENT);
      if (r == ep * 8u - 1u)
        __hip_atomic_store(bar + 288, ep, __ATOMIC_RELAXED, AGENT);
    }
    while (__hip_atomic_load(bar + 288, __ATOMIC_RELAXED, AGENT) < ep)
      __builtin_amdgcn_s_sleep(8);
  }
  __syncthreads();
}

__global__ __launch_bounds__(GTHR) void k_main(
    const unsigned short* __restrict__ Wvh, const unsigned short* __restrict__ Woh,
    const unsigned short* __restrict__ fc1h, const float* __restrict__ fc1b,
    const unsigned short* __restrict__ fc2h, const float* __restrict__ fc2b,
    const float* __restrict__ lng, const float* __restrict__ lnb,
    const float* __restrict__ lzg, const float* __restrict__ lzb,
    float* __restrict__ S, float* __restrict__ ocum,
    float* __restrict__ vbuf, unsigned short* __restrict__ hbufB,
    unsigned* __restrict__ bar) {
  // LDS: phase A: per cell c: z f32 @ c*2048, x2 f32 @ c*2048+1024  (80KB)
  //      phase B: v f32 [5][1024] @ 0; h bf16 [5][4096] @ float 5120 (40KB)
  __shared__ __align__(16) float lds[20480];
  __shared__ float4 stats[TKL];
  __shared__ float part[4][4][5];

  const int tid = threadIdx.x;
  const int lane = tid & 63;
  const int bwave = tid >> 6;
  const int gw = blockIdx.x * 16 + bwave;
  const float g1 = lng[tid], b1 = lnb[tid], g2 = lzg[tid], b2 = lzb[tid];
  unsigned ep = 0;

  for (int t = 0; t < NWFR; ++t) {
    const int alo = (t - (NT - 1)) > 0 ? (t - (NT - 1)) : 0;
    const int ahi = t < (TKL - 1) ? t : (TKL - 1);
    const int nc = ahi - alo + 1;
    const int nS = nc << 8;  // 16B slots per array (256 per cell row)

    // ---- stage S & ocum rows into LDS (batched 8B coherent loads) ----
    {
      ull aS[3][2], aO[3][2];
#pragma unroll
      for (int r = 0; r < 3; ++r) {
        const int s = tid + (r << 10);
        if (s < nS) {
          const int c = s >> 8, e = (s & 255) << 2;
          const int a = alo + c, i = t - a;
          const float* ps = S + i * MDIM + e;
          const float* po = ocum + a * MDIM + e;
          aS[r][0] = gld8(ps); aS[r][1] = gld8(ps + 2);
          aO[r][0] = gld8(po); aO[r][1] = gld8(po + 2);
        }
      }
#pragma unroll
      for (int r = 0; r < 3; ++r) {
        const int s = tid + (r << 10);
        if (s < nS) {
          const int c = s >> 8, e = (s & 255) << 2;
          *(ull*)(lds + (c << 11) + e) = aS[r][0];
          *(ull*)(lds + (c << 11) + e + 2) = aS[r][1];
          *(ull*)(lds + (c << 11) + MDIM + e) = aO[r][0];
          *(ull*)(lds + (c << 11) + MDIM + e + 2) = aO[r][1];
        }
      }
    }
    __syncthreads();

    // ---- LN stats from LDS: one wave per cell ----
    if (bwave < nc) {
      float sv[16], tv[16];
#pragma unroll
      for (int k = 0; k < 16; ++k) {
        const float a_ = lds[(bwave << 11) + lane + (k << 6)];
        const float o_ = lds[(bwave << 11) + MDIM + lane + (k << 6)];
        sv[k] = a_; tv[k] = a_ + o_;
      }
      float s1 = 0.f, t1 = 0.f;
#pragma unroll
      for (int k = 0; k < 16; ++k) { s1 += sv[k]; t1 += tv[k]; }
      const float mu_s = wred(s1) * (1.0f / MDIM);
      const float mu_t = wred(t1) * (1.0f / MDIM);
      float s2 = 0.f, t2 = 0.f;
#pragma unroll
      for (int k = 0; k < 16; ++k) {
        float d = sv[k] - mu_s; s2 += d * d;
        float e = tv[k] - mu_t; t2 += e * e;
      }
      const float var_s = wred(s2) * (1.0f / MDIM);
      const float var_t = wred(t2) * (1.0f / MDIM);
      if (lane == 0)
        stats[bwave] = make_float4(mu_s, rsqrtf(var_s + 1e-5f),
                                   mu_t, rsqrtf(var_t + 1e-5f));
    }
    __syncthreads();

    // ---- elementwise in place: z = LN1(s), x2 = LN2(s+o)+(s+o) ----
#pragma unroll
    for (int c = 0; c < TKL; ++c)
      if (c < nc) {
        const float4 st = stats[c];
        const float sv = lds[(c << 11) + tid];
        const float ov = lds[(c << 11) + MDIM + tid];
        const float tv = sv + ov;
        lds[(c << 11) + tid] = (sv - st.x) * st.y * g1 + b1;
        lds[(c << 11) + MDIM + tid] = (tv - st.z) * st.w * g2 + b2 + tv;
      }
    __syncthreads();

    // ---- Phase A: Wv (pinned slots, 2 rows each) + fc1 (row gw, all cells) ----
#pragma unroll
    for (int r = 0; r < 2; ++r) {
      const int s = gw + (r ? NWAVES : 0);
      if (s < TKL * 512) {
        const int a = s >> 9, i = t - a;
        if (a >= alo && a <= ahi && i != NT - 1) {
          const int c = a - alo;
          const int row0 = (s & 511) << 1;
          const uint2* w2 = (const uint2*)(Wvh + ((size_t)a << 20) + ((size_t)row0 << 10));
          const float4* z4 = (const float4*)(lds + (c << 11));
          float a0 = 0.f, a1 = 0.f;
#pragma unroll
          for (int k = 0; k < 4; ++k) {
            const int g = lane + (k << 6);
            const uint2 wa = w2[g], wb = w2[256 + g];
            const float4 z = z4[g];
            a0 += b2f(wa.x & 0xffff) * z.x + b2f(wa.x >> 16) * z.y +
                  b2f(wa.y & 0xffff) * z.z + b2f(wa.y >> 16) * z.w;
            a1 += b2f(wb.x & 0xffff) * z.x + b2f(wb.x >> 16) * z.y +
                  b2f(wb.y & 0xffff) * z.z + b2f(wb.y >> 16) * z.w;
          }
          a0 = wred(a0); a1 = wred(a1);
          if (lane == 0) {
            ull pv = (ull)__float_as_uint(a0) | ((ull)__float_as_uint(a1) << 32);
            gst8(vbuf + a * MDIM + row0, pv);
          }
        }
      }
    }
    {  // fc1 row j = gw for all active cells; gelu on gathered lanes
      const int j = gw;
      const uint2* w2 = (const uint2*)(fc1h + ((size_t)j << 10));
      float wf[16];
#pragma unroll
      for (int k = 0; k < 4; ++k) {
        const uint2 w = w2[lane + (k << 6)];
        wf[4 * k] = b2f(w.x & 0xffff); wf[4 * k + 1] = b2f(w.x >> 16);
        wf[4 * k + 2] = b2f(w.y & 0xffff); wf[4 * k + 3] = b2f(w.y >> 16);
      }
      const float bias = fc1b[j];
      float sel = 0.f;
#pragma unroll
      for (int c = 0; c < TKL; ++c)
        if (c < nc) {
          const float4* x4 = (const float4*)(lds + (c << 11) + MDIM);
          float acc = 0.f;
#pragma unroll
          for (int k = 0; k < 4; ++k) {
            const float4 x = x4[lane + (k << 6)];
            acc += wf[4 * k] * x.x + wf[4 * k + 1] * x.y +
                   wf[4 * k + 2] * x.z + wf[4 * k + 3] * x.w;
          }
          acc = wred(acc);
          sel = (lane == c) ? acc : sel;
        }
      const float xg = sel + bias;
      const float ge = 0.5f * xg * (1.0f + erff(xg * 0.70710678118654752f));
      if (lane < nc) {
        const unsigned hb = (unsigned)f2b(ge);
        const unsigned short* hp = hbufB + ((size_t)(alo + lane) << 12) + j;
        asm volatile("global_store_short %0, %1, off sc0 sc1" :: "v"(hp), "v"(hb) : "memory");
      }
    }
    ++ep; gbar(bar, ep);

    // ---- Phase B (2 chunks of <=5 cells): fc2 + Wo/ocum ----
    for (int chunk = 0; chunk < 2; ++chunk) {
      const int c0 = chunk * 5;
      const int nch = (nc - c0) < 5 ? (nc - c0) : 5;
      if (nch <= 0) break;  // uniform across grid
      __syncthreads();
      const int nV = nch << 8;  // 16B slots (v, f32)
      const int nH = nch << 9;  // 16B slots (h, bf16 x8)
      {
        ull aV[2][2], aH[3][2];
#pragma unroll
        for (int r = 0; r < 2; ++r) {
          const int s = tid + (r << 10);
          if (s < nV) {
            const int c = s >> 8, e = (s & 255) << 2;
            const float* pv = vbuf + (alo + c0 + c) * MDIM + e;
            aV[r][0] = gld8(pv); aV[r][1] = gld8(pv + 2);
          }
        }
#pragma unroll
        for (int r = 0; r < 3; ++r) {
          const int s = tid + (r << 10);
          if (s < nH) {
            const int c = s >> 9, e = s & 511;
            const unsigned short* ph = hbufB + ((size_t)(alo + c0 + c) << 12) + (e << 3);
            aH[r][0] = gld8(ph); aH[r][1] = gld8(ph + 4);
          }
        }
        unsigned short* hlds = (unsigned short*)(lds + 5120);
#pragma unroll
        for (int r = 0; r < 2; ++r) {
          const int s = tid + (r << 10);
          if (s < nV) {
            const int c = s >> 8, e = (s & 255) << 2;
            *(ull*)(lds + (c << 10) + e) = aV[r][0];
            *(ull*)(lds + (c << 10) + e + 2) = aV[r][1];
          }
        }
#pragma unroll
        for (int r = 0; r < 3; ++r) {
          const int s = tid + (r << 10);
          if (s < nH) {
            const int c = s >> 9, e = s & 511;
            *(ull*)(hlds + (c << 12) + (e << 3)) = aH[r][0];
            *(ull*)(hlds + (c << 12) + (e << 3) + 4) = aH[r][1];
          }
        }
      }
      __syncthreads();
      {  // fc2: 4 rows/block x 4 k-quarters, bf16 h from LDS
        const int rl = bwave & 3, kq = bwave >> 2;
        const int jrow = (blockIdx.x << 2) | rl;
        const uint4* wr = (const uint4*)fc2h + ((size_t)jrow << 9) + (kq << 7);
        const uint4 w0 = wr[lane], w1 = wr[lane + 64];
        const unsigned short* hlds = (const unsigned short*)(lds + 5120);
#pragma unroll
        for (int c = 0; c < 5; ++c)
          if (c < nch) {
            const uint4* h4 = (const uint4*)(hlds + (c << 12)) + (kq << 7);
            const uint4 h0 = h4[lane], h1 = h4[lane + 64];
            float acc = 0.f;
            acc = dot8u(make_uint2(w0.x, w0.y), make_uint2(h0.x, h0.y), acc);
            acc = dot8u(make_uint2(w0.z, w0.w), make_uint2(h0.z, h0.w), acc);
            acc = dot8u(make_uint2(w1.x, w1.y), make_uint2(h1.x, h1.y), acc);
            acc = dot8u(make_uint2(w1.z, w1.w), make_uint2(h1.z, h1.w), acc);
            acc = wred(acc);
            if (lane == 0) part[rl][kq][c] = acc;
          }
      }
      __syncthreads();
      if (tid < 20) {
        const int rl = tid & 3, c = tid >> 2;
        if (c < nch) {
          const int jrow = (blockIdx.x << 2) | rl;
          const int a = alo + c0 + c, i = t - a;
          gst(S + i * MDIM + jrow, part[rl][0][c] + part[rl][1][c] +
                                       part[rl][2][c] + part[rl][3][c] + fc2b[jrow]);
        }
      }
      // Wo: pinned slots, early ocum load, 8B RMW by exclusive owner
#pragma unroll
      for (int r = 0; r < 2; ++r) {
        const int s = gw + (r ? NWAVES : 0);
        if (s < TKL * 512) {
          const int a = s >> 9, i = t - a;
          if (a >= alo + c0 && a < alo + c0 + nch && i != NT - 1) {
            const int c = a - (alo + c0);
            const int row0 = (s & 511) << 1;
            const ull ov = gld8(ocum + a * MDIM + row0);
            const uint2* w2 = (const uint2*)(Woh + ((size_t)a << 20) + ((size_t)row0 << 10));
            const float4* v4 = (const float4*)(lds + (c << 10));
            float a0 = 0.f, a1 = 0.f;
#pragma unroll
            for (int k = 0; k < 4; ++k) {
              const int g = lane + (k << 6);
              const uint2 wa = w2[g], wb = w2[256 + g];
              const float4 v = v4[g];
              a0 += b2f(wa.x & 0xffff) * v.x + b2f(wa.x >> 16) * v.y +
                    b2f(wa.y & 0xffff) * v.z + b2f(wa.y >> 16) * v.w;
              a1 += b2f(wb.x & 0xffff) * v.x + b2f(wb.x >> 16) * v.y +
                    b2f(wb.y & 0xffff) * v.z + b2f(wb.y >> 16) * v.w;
            }
            a0 = wred(a0); a1 = wred(a1);
            if (lane == 0) {
              const float o0 = __uint_as_float((unsigned)ov) + a0;
              const float o1 = __uint_as_float((unsigned)(ov >> 32)) + a1;
              const ull nv = (ull)__float_as_uint(o0) | ((ull)__float_as_uint(o1) << 32);
              gst8(ocum + a * MDIM + row0, nv);
            }
          }
        }
      }
    }
    ++ep; gbar(bar, ep);
  }
}

extern "C" void kernel_launch(void* const* d_in, const int* in_sizes, int n_in,
                              void* d_out, int out_size, void* d_ws, size_t ws_size,
                              hipStream_t stream) {
  const float* x    = (const float*)d_in[0];
  const float* W    = (const float*)d_in[1];
  const float* Wv   = (const float*)d_in[4];
  const float* Wo   = (const float*)d_in[5];
  const float* lng  = (const float*)d_in[6];
  const float* lnb  = (const float*)d_in[7];
  const float* lzg  = (const float*)d_in[8];
  const float* lzb  = (const float*)d_in[9];
  const float* fc1w = (const float*)d_in[10];
  const float* fc1b = (const float*)d_in[11];
  const float* fc2w = (const float*)d_in[12];
  const float* fc2b = (const float*)d_in[13];
  float* S = (float*)d_out;

  float* xcf  = (float*)d_ws;                     // 30720 f32
  float* ocum = xcf + 30720;                      // 10240
  float* vbuf = ocum + 10240;                     // 10240
  unsigned* bar = (unsigned*)(vbuf + 10240);      // 4096 f32 slots
  unsigned short* hbufB = (unsigned short*)(vbuf + 10240 + 4096);  // 40960 ushort
  unsigned short* Wvh  = hbufB + 40960;
  unsigned short* Woh  = Wvh + (size_t)TKL * MDIM * MDIM;
  unsigned short* fc1h = Woh + (size_t)TKL * MDIM * MDIM;
  unsigned short* fc2h = fc1h + (size_t)H4 * MDIM;

  hipLaunchKernelGGL(k_cvt, dim3(TKL * MDIM * MDIM / 8 / 256), dim3(256), 0, stream,
                     Wv, Wvh, TKL * MDIM * MDIM / 8);
  hipLaunchKernelGGL(k_cvt, dim3(TKL * MDIM * MDIM / 8 / 256), dim3(256), 0, stream,
                     Wo, Woh, TKL * MDIM * MDIM / 8);
  hipLaunchKernelGGL(k_cvt, dim3(H4 * MDIM / 8 / 256), dim3(256), 0, stream,
                     fc1w, fc1h, H4 * MDIM / 8);
  hipLaunchKernelGGL(k_cvt, dim3(H4 * MDIM / 8 / 256), dim3(256), 0, stream,
                     fc2w, fc2h, H4 * MDIM / 8);
  hipLaunchKernelGGL(k_xcf, dim3((NT * MDIM + 255) / 256), dim3(256), 0, stream, x, xcf);
  hipLaunchKernelGGL(k_s0, dim3(NT * MDIM / 4), dim3(256), 0, stream, xcf, W, S);
  hipMemsetAsync(ocum, 0, TKL * MDIM * sizeof(float), stream);
  hipMemsetAsync(bar, 0, 2048, stream);

  void* args[] = {(void*)&Wvh, (void*)&Woh, (void*)&fc1h, (void*)&fc1b,
                  (void*)&fc2h, (void*)&fc2b, (void*)&lng, (void*)&lnb,
                  (void*)&lzg, (void*)&lzb, (void*)&S,   (void*)&ocum,
                  (void*)&vbuf, (void*)&hbufB, (void*)&bar};
  hipLaunchCooperativeKernel((void*)k_main, dim3(GBLK), dim3(GTHR), args, 0, stream);
}

// Round 5
// 1296.666 us; speedup vs baseline: 2.6823x; 1.0962x over previous
//
#include <hip/hip_runtime.h>

#define MDIM 1024
#define H4   4096
#define TKL  10
#define NT   30
#define NWFR 39
#define GBLK 256
#define GTHR 1024
#define AGENT __HIP_MEMORY_SCOPE_AGENT

#if defined(__has_builtin)
#if __has_builtin(__builtin_amdgcn_fdot2)
#define HAS_FDOT2 1
#endif
#endif

typedef _Float16 h2v __attribute__((ext_vector_type(2)));
union U16 { uint4 u; h2v h[4]; _Float16 f[8]; };
union HU { _Float16 f; unsigned short s; };

__device__ __forceinline__ float wred(float v) {
#pragma unroll
  for (int o = 32; o; o >>= 1) v += __shfl_xor(v, o, 64);
  return v;
}

__device__ __forceinline__ float dot16(const U16& w, const U16& x, float acc) {
#ifdef HAS_FDOT2
  acc = __builtin_amdgcn_fdot2(w.h[0], x.h[0], acc, false);
  acc = __builtin_amdgcn_fdot2(w.h[1], x.h[1], acc, false);
  acc = __builtin_amdgcn_fdot2(w.h[2], x.h[2], acc, false);
  acc = __builtin_amdgcn_fdot2(w.h[3], x.h[3], acc, false);
#else
#pragma unroll
  for (int e = 0; e < 8; ++e) acc += (float)w.f[e] * (float)x.f[e];
#endif
  return acc;
}

// ---- f32 -> f16 packed (8/thread) ----
__global__ void k_cvt(const float* __restrict__ in, _Float16* __restrict__ out, int n8) {
  int g = blockIdx.x * blockDim.x + threadIdx.x;
  if (g >= n8) return;
  const float4* p = (const float4*)in;
  float4 a = p[2 * g], b = p[2 * g + 1];
  U16 o;
  o.f[0] = (_Float16)a.x; o.f[1] = (_Float16)a.y;
  o.f[2] = (_Float16)a.z; o.f[3] = (_Float16)a.w;
  o.f[4] = (_Float16)b.x; o.f[5] = (_Float16)b.y;
  o.f[6] = (_Float16)b.z; o.f[7] = (_Float16)b.w;
  ((uint4*)out)[g] = o.u;
}

__global__ void k_xcf(const float* __restrict__ x, float* __restrict__ xcf) {
  int idx = blockIdx.x * blockDim.x + threadIdx.x;
  if (idx >= NT * MDIM) return;
  int i = idx >> 10, m = idx & (MDIM - 1);
  int c = m & 31, s = m >> 5;
  const float* p = x + c * (32 * 360) + s * 360 + i * 12;
  float acc = 0.f;
#pragma unroll
  for (int k = 0; k < 12; ++k) acc += p[k];
  xcf[idx] = acc * (1.0f / 12.0f);
}

// writes S master (f32) AND the diagonal version of the S mirror: Smir[i][i]
__global__ void k_s0(const float* __restrict__ xcf, const float* __restrict__ W,
                     float* __restrict__ S, float* __restrict__ Smir) {
  int wid = (blockIdx.x * blockDim.x + threadIdx.x) >> 6;
  int lane = threadIdx.x & 63;
  if (wid >= NT * MDIM) return;
  int i = wid >> 10, m = wid & (MDIM - 1);
  const float4* wr = (const float4*)(W + (size_t)m * MDIM);
  const float4* xr = (const float4*)(xcf + i * MDIM);
  float acc = 0.f;
#pragma unroll
  for (int k = 0; k < 4; ++k) {
    float4 w = wr[lane + (k << 6)];
    float4 xv = xr[lane + (k << 6)];
    acc += w.x * xv.x + w.y * xv.y + w.z * xv.z + w.w * xv.w;
  }
  acc = wred(acc);
  if (lane == 0) {
    int e = m & ~1;
    float ang = (float)i / powf(10000.0f, (float)e / 512.0f);
    float pe = (m & 1) ? cosf(ang) : sinf(ang);
    float val = acc + pe;
    S[wid] = val;
    Smir[((size_t)i * NT + i) * MDIM + m] = val;
  }
}

// two-level fence-free barrier (proven R4): 8 leaves + root + go flag
__device__ __forceinline__ void gbar(unsigned* bar, unsigned ep) {
  asm volatile("s_waitcnt vmcnt(0)" ::: "memory");
  __syncthreads();
  if (threadIdx.x == 0) {
    unsigned* leaf = bar + ((blockIdx.x & 7) << 5);
    const unsigned prev = __hip_atomic_fetch_add(leaf, 1u, __ATOMIC_RELAXED, AGENT);
    if (prev == ep * 32u - 1u) {
      const unsigned r = __hip_atomic_fetch_add(bar + 256, 1u, __ATOMIC_RELAXED, AGENT);
      if (r == ep * 8u - 1u)
        __hip_atomic_store(bar + 288, ep, __ATOMIC_RELAXED, AGENT);
    }
    while (__hip_atomic_load(bar + 288, __ATOMIC_RELAXED, AGENT) < ep)
      __builtin_amdgcn_s_sleep(2);
  }
  __syncthreads();
}

__global__ __launch_bounds__(GTHR) void k_main(
    const _Float16* __restrict__ Wvh, const _Float16* __restrict__ Woh,
    const _Float16* __restrict__ fc1h, const float* __restrict__ fc1b,
    const _Float16* __restrict__ fc2h, const float* __restrict__ fc2b,
    const float* __restrict__ lng, const float* __restrict__ lnb,
    const float* __restrict__ lzg, const float* __restrict__ lzb,
    float* __restrict__ S, float* __restrict__ ocum,
    float* __restrict__ Smir, float* __restrict__ Omir, float* __restrict__ vmir,
    _Float16* __restrict__ hmir, unsigned* __restrict__ bar) {
  // LDS: fc1L[16][1024] f16 | fc2L[8][4096] f16 | zL[10][1024] | x2L[10][1024] | vstL[3][1024]
  // phase-B hL[5][4096] f16 reuses zL+x2L (40960 B)
  __shared__ __align__(16) unsigned char smem[145408];
  __shared__ float red[8][2][4];
  __shared__ float vgs[3][16];
  __shared__ _Float16 hgelL[16][16];
  __shared__ float part[8][2][10];

  _Float16* fc1L = (_Float16*)(smem);
  _Float16* fc2L = (_Float16*)(smem + 32768);
  _Float16* zL   = (_Float16*)(smem + 98304);
  _Float16* x2L  = (_Float16*)(smem + 118784);
  _Float16* vstL = (_Float16*)(smem + 139264);
  _Float16* hL   = zL;  // phase-B reuse

  const int tid = threadIdx.x;
  const int lane = tid & 63;
  const int bwave = tid >> 6;
  const int b = blockIdx.x;
  unsigned ep = 0;

  // cross-replay safety + cross-dispatch visibility
  __builtin_amdgcn_fence(__ATOMIC_ACQUIRE, "agent");

  // persist fc1 (16 rows) and fc2 (8 rows, used by b>=128) in LDS
  {
    const _Float16* s1 = fc1h + (size_t)b * 16384;
#pragma unroll
    for (int r = 0; r < 2; ++r) {
      const int s = tid + (r << 10);
      *(uint4*)(fc1L + (s << 3)) = *(const uint4*)(s1 + (s << 3));
    }
    const _Float16* s2 = fc2h + (size_t)(b & 127) * 32768;
#pragma unroll
    for (int r = 0; r < 4; ++r) {
      const int s = tid + (r << 10);
      *(uint4*)(fc2L + (s << 3)) = *(const uint4*)(s2 + (s << 3));
    }
  }
  __syncthreads();

  for (int t = 0; t < NWFR; ++t) {
    const int alo = (t - (NT - 1)) > 0 ? (t - (NT - 1)) : 0;
    const int ahi = t < (TKL - 1) ? t : (TKL - 1);
    const int nc = ahi - alo + 1;
    const float* Smirt = Smir + (size_t)t * NT * MDIM;
    const float* Omirt = Omir + (size_t)t * TKL * MDIM;

    // ---- staging + LN + z/x2 (cached reads of version-t mirrors) ----
    for (int cb = 0; cb < nc; cb += 8) {
      const int cp = tid >> 7, idx = tid & 127, wh = (tid >> 6) & 1;
      const int c = cb + cp;
      const bool act = c < nc;
      float sv[8], tv[8];
      if (act) {
        const int a = alo + c, i = t - a;
        const float4* sp = (const float4*)(Smirt + (size_t)i * MDIM + (idx << 3));
        const float4* op = (const float4*)(Omirt + (size_t)a * MDIM + (idx << 3));
        const float4 sA = sp[0], sB = sp[1], oA = op[0], oB = op[1];
        sv[0] = sA.x; sv[1] = sA.y; sv[2] = sA.z; sv[3] = sA.w;
        sv[4] = sB.x; sv[5] = sB.y; sv[6] = sB.z; sv[7] = sB.w;
        tv[0] = sv[0] + oA.x; tv[1] = sv[1] + oA.y; tv[2] = sv[2] + oA.z; tv[3] = sv[3] + oA.w;
        tv[4] = sv[4] + oB.x; tv[5] = sv[5] + oB.y; tv[6] = sv[6] + oB.z; tv[7] = sv[7] + oB.w;
      } else {
#pragma unroll
        for (int e = 0; e < 8; ++e) { sv[e] = 0.f; tv[e] = 0.f; }
      }
      float s1 = 0.f, t1 = 0.f;
#pragma unroll
      for (int e = 0; e < 8; ++e) { s1 += sv[e]; t1 += tv[e]; }
      s1 = wred(s1); t1 = wred(t1);
      if (!lane) { red[cp][wh][0] = s1; red[cp][wh][1] = t1; }
      __syncthreads();
      const float mu_s = (red[cp][0][0] + red[cp][1][0]) * (1.0f / MDIM);
      const float mu_t = (red[cp][0][1] + red[cp][1][1]) * (1.0f / MDIM);
      float s2 = 0.f, t2 = 0.f;
#pragma unroll
      for (int e = 0; e < 8; ++e) {
        float d = sv[e] - mu_s; s2 += d * d;
        float f = tv[e] - mu_t; t2 += f * f;
      }
      s2 = wred(s2); t2 = wred(t2);
      if (!lane) { red[cp][wh][2] = s2; red[cp][wh][3] = t2; }
      __syncthreads();
      if (act) {
        const float rs = rsqrtf((red[cp][0][2] + red[cp][1][2]) * (1.0f / MDIM) + 1e-5f);
        const float rt = rsqrtf((red[cp][0][3] + red[cp][1][3]) * (1.0f / MDIM) + 1e-5f);
        const float4* g1p = (const float4*)(lng + (idx << 3));
        const float4* b1p = (const float4*)(lnb + (idx << 3));
        const float4* g2p = (const float4*)(lzg + (idx << 3));
        const float4* b2p = (const float4*)(lzb + (idx << 3));
        float g1[8], b1[8], g2[8], b2[8];
        { float4 u = g1p[0], v = g1p[1];
          g1[0]=u.x; g1[1]=u.y; g1[2]=u.z; g1[3]=u.w; g1[4]=v.x; g1[5]=v.y; g1[6]=v.z; g1[7]=v.w; }
        { float4 u = b1p[0], v = b1p[1];
          b1[0]=u.x; b1[1]=u.y; b1[2]=u.z; b1[3]=u.w; b1[4]=v.x; b1[5]=v.y; b1[6]=v.z; b1[7]=v.w; }
        { float4 u = g2p[0], v = g2p[1];
          g2[0]=u.x; g2[1]=u.y; g2[2]=u.z; g2[3]=u.w; g2[4]=v.x; g2[5]=v.y; g2[6]=v.z; g2[7]=v.w; }
        { float4 u = b2p[0], v = b2p[1];
          b2[0]=u.x; b2[1]=u.y; b2[2]=u.z; b2[3]=u.w; b2[4]=v.x; b2[5]=v.y; b2[6]=v.z; b2[7]=v.w; }
        U16 zz, xx;
#pragma unroll
        for (int e = 0; e < 8; ++e) {
          zz.f[e] = (_Float16)((sv[e] - mu_s) * rs * g1[e] + b1[e]);
          const float u = tv[e];
          xx.f[e] = (_Float16)((u - mu_t) * rt * g2[e] + b2[e] + u);
        }
        *(uint4*)(zL + c * MDIM + (idx << 3)) = zz.u;
        *(uint4*)(x2L + c * MDIM + (idx << 3)) = xx.u;
      }
      __syncthreads();
    }

    // ---- Phase A: Wv groups (16 rows/group, <=3 groups/block) + fc1 (LDS rows) ----
#pragma unroll
    for (int r = 0; r < 3; ++r) {
      const int g = b + (r << 8);
      if (g < 640) {
        const int a = g >> 6, rg = g & 63, i = t - a;
        if (a >= alo && a <= ahi && i != NT - 1) {
          const int c = a - alo;
          const _Float16* wp = Wvh + ((size_t)a << 20) + ((size_t)((rg << 4) | bwave) << 10);
          U16 w0, w1, z0, z1;
          w0.u = *(const uint4*)(wp + (lane << 3));
          w1.u = *(const uint4*)(wp + 512 + (lane << 3));
          z0.u = *(const uint4*)(zL + c * MDIM + (lane << 3));
          z1.u = *(const uint4*)(zL + c * MDIM + 512 + (lane << 3));
          float acc = dot16(w0, z0, 0.f);
          acc = dot16(w1, z1, acc);
          acc = wred(acc);
          if (!lane) vgs[r][bwave] = acc;
        }
      }
    }
    {  // fc1: row (b*16+bwave) for all active cells
      U16 f0, f1;
      f0.u = *(const uint4*)(fc1L + bwave * MDIM + (lane << 3));
      f1.u = *(const uint4*)(fc1L + bwave * MDIM + 512 + (lane << 3));
      const float bias = fc1b[(b << 4) | bwave];
      float sel = 0.f;
#pragma unroll
      for (int c = 0; c < TKL; ++c)
        if (c < nc) {
          U16 x0, x1;
          x0.u = *(const uint4*)(x2L + c * MDIM + (lane << 3));
          x1.u = *(const uint4*)(x2L + c * MDIM + 512 + (lane << 3));
          float acc = dot16(f0, x0, 0.f);
          acc = dot16(f1, x1, acc);
          acc = wred(acc);
          sel = (lane == c) ? acc : sel;
        }
      const float xg = sel + bias;
      const float ge = 0.5f * xg * (1.0f + erff(xg * 0.70710678118654752f));
      if (lane < nc) hgelL[bwave][lane] = (_Float16)ge;
    }
    __syncthreads();
    // v-store (waves 13..15), h-store (waves 0..nc-1): uncached write-through
    if (bwave >= 13) {
      const int r = bwave - 13;
      const int g = b + (r << 8);
      if (g < 640) {
        const int a = g >> 6, rg = g & 63, i = t - a;
        if (a >= alo && a <= ahi && i != NT - 1 && lane < 16)
          __hip_atomic_store(vmir + ((size_t)t * TKL + a) * MDIM + (rg << 4) + lane,
                             vgs[r][lane], __ATOMIC_RELAXED, AGENT);
      }
    }
    if (bwave < nc && lane < 16) {
      HU hu; hu.f = hgelL[lane][bwave];
      __hip_atomic_store(
          (unsigned short*)(hmir + ((size_t)t * TKL + alo + bwave) * H4 + (b << 4)) + lane,
          hu.s, __ATOMIC_RELAXED, AGENT);
    }
    ++ep; gbar(bar, ep);

    // ---- Phase B: Wo/ocum (all blocks) + fc2 (blocks >= 128) ----
#pragma unroll
    for (int r = 0; r < 3; ++r) {
      const int g = b + (r << 8);
      if (g < 640) {
        const int a = g >> 6, i = t - a;
        if (a >= alo && a <= ahi && i != NT - 1)
          vstL[(r << 10) + tid] = (_Float16)vmir[((size_t)t * TKL + a) * MDIM + tid];
      }
    }
    __syncthreads();
#pragma unroll
    for (int r = 0; r < 3; ++r) {
      const int g = b + (r << 8);
      if (g < 640) {
        const int a = g >> 6, rg = g & 63, i = t - a;
        if (a >= alo && a <= ahi && i != NT - 1) {
          const _Float16* wp = Woh + ((size_t)a << 20) + ((size_t)((rg << 4) | bwave) << 10);
          U16 w0, w1, v0, v1;
          w0.u = *(const uint4*)(wp + (lane << 3));
          w1.u = *(const uint4*)(wp + 512 + (lane << 3));
          v0.u = *(const uint4*)(vstL + (r << 10) + (lane << 3));
          v1.u = *(const uint4*)(vstL + (r << 10) + 512 + (lane << 3));
          float acc = dot16(w0, v0, 0.f);
          acc = dot16(w1, v1, acc);
          acc = wred(acc);
          if (!lane) vgs[r][bwave] = acc;
        }
      }
    }
    __syncthreads();
    if (bwave >= 13) {  // ocum RMW (uncached, owner-exclusive) + next-version mirror
      const int r = bwave - 13;
      const int g = b + (r << 8);
      if (g < 640) {
        const int a = g >> 6, rg = g & 63, i = t - a;
        if (a >= alo && a <= ahi && i != NT - 1 && lane < 16) {
          const int R = (rg << 4) + lane;
          const float old = __hip_atomic_load(ocum + a * MDIM + R, __ATOMIC_RELAXED, AGENT);
          const float nv = old + vgs[r][lane];
          __hip_atomic_store(ocum + a * MDIM + R, nv, __ATOMIC_RELAXED, AGENT);
          __hip_atomic_store(Omir + ((size_t)(t + 1) * TKL + a) * MDIM + R, nv,
                             __ATOMIC_RELAXED, AGENT);
        }
      }
    }
    if (b >= 128) {  // fc2: 8 LDS-resident rows, h staged in 2 chunks of 5 cells
      const int rl = bwave & 7, kh = bwave >> 3;
#pragma unroll
      for (int ch = 0; ch < 2; ++ch) {
#pragma unroll
        for (int r = 0; r < 3; ++r) {
          const int s = tid + (r << 10);
          if (s < 2560) {
            const int q = s >> 9, idx = s & 511;
            const int c = ch * 5 + q;
            if (c < nc)
              *(uint4*)(hL + q * H4 + (idx << 3)) =
                  *(const uint4*)(hmir + ((size_t)t * TKL + alo + c) * H4 + (idx << 3));
          }
        }
        __syncthreads();
#pragma unroll
        for (int q = 0; q < 5; ++q) {
          const int c = ch * 5 + q;
          if (c < nc) {
            float acc = 0.f;
#pragma unroll
            for (int kk = 0; kk < 4; ++kk) {
              U16 w, h;
              const int off = (kh << 11) + (kk << 9) + (lane << 3);
              w.u = *(const uint4*)(fc2L + rl * H4 + off);
              h.u = *(const uint4*)(hL + q * H4 + off);
              acc = dot16(w, h, acc);
            }
            acc = wred(acc);
            if (!lane) part[rl][kh][c] = acc;
          }
        }
        __syncthreads();
      }
      if (bwave < nc && lane < 8) {
        const int a = alo + bwave, i = t - a;
        const int j = ((b - 128) << 3) | lane;
        const float val = part[lane][0][bwave] + part[lane][1][bwave] + fc2b[j];
        S[i * MDIM + j] = val;  // f32 master (d_out), block-private lines
        __hip_atomic_store(Smir + ((size_t)(t + 1) * NT + i) * MDIM + j, val,
                           __ATOMIC_RELAXED, AGENT);
      }
    }
    ++ep; gbar(bar, ep);
  }
}

extern "C" void kernel_launch(void* const* d_in, const int* in_sizes, int n_in,
                              void* d_out, int out_size, void* d_ws, size_t ws_size,
                              hipStream_t stream) {
  const float* x    = (const float*)d_in[0];
  const float* W    = (const float*)d_in[1];
  const float* Wv   = (const float*)d_in[4];
  const float* Wo   = (const float*)d_in[5];
  const float* lng  = (const float*)d_in[6];
  const float* lnb  = (const float*)d_in[7];
  const float* lzg  = (const float*)d_in[8];
  const float* lzb  = (const float*)d_in[9];
  const float* fc1w = (const float*)d_in[10];
  const float* fc1b = (const float*)d_in[11];
  const float* fc2w = (const float*)d_in[12];
  const float* fc2b = (const float*)d_in[13];
  float* S = (float*)d_out;

  float* xcf  = (float*)d_ws;                 // 30720 f32
  float* ocum = xcf + 30720;                  // 10240 f32
  unsigned* bar = (unsigned*)(ocum + 10240);  // 512 u32
  float* Smir = (float*)(bar + 512);          // 40*30*1024 f32
  float* Omir = Smir + 1228800;               // 40*10*1024 f32
  float* vmir = Omir + 409600;                // 40*10*1024 f32
  _Float16* hmir = (_Float16*)(vmir + 409600);  // 40*10*4096 f16
  _Float16* Wvh  = hmir + 1638400;
  _Float16* Woh  = Wvh + 10485760;
  _Float16* fc1h = Woh + 10485760;
  _Float16* fc2h = fc1h + 4194304;

  hipLaunchKernelGGL(k_cvt, dim3(5120), dim3(256), 0, stream, Wv, Wvh, 1310720);
  hipLaunchKernelGGL(k_cvt, dim3(5120), dim3(256), 0, stream, Wo, Woh, 1310720);
  hipLaunchKernelGGL(k_cvt, dim3(2048), dim3(256), 0, stream, fc1w, fc1h, 524288);
  hipLaunchKernelGGL(k_cvt, dim3(2048), dim3(256), 0, stream, fc2w, fc2h, 524288);
  hipLaunchKernelGGL(k_xcf, dim3((NT * MDIM + 255) / 256), dim3(256), 0, stream, x, xcf);
  hipLaunchKernelGGL(k_s0, dim3(NT * MDIM / 4), dim3(256), 0, stream, xcf, W, S, Smir);
  hipMemsetAsync(ocum, 0, 10240 * sizeof(float), stream);
  hipMemsetAsync(Omir, 0, 409600 * sizeof(float), stream);
  hipMemsetAsync(bar, 0, 2048, stream);

  void* args[] = {(void*)&Wvh, (void*)&Woh, (void*)&fc1h, (void*)&fc1b,
                  (void*)&fc2h, (void*)&fc2b, (void*)&lng, (void*)&lnb,
                  (void*)&lzg, (void*)&lzb, (void*)&S,   (void*)&ocum,
                  (void*)&Smir, (void*)&Omir, (void*)&vmir, (void*)&hmir,
                  (void*)&bar};
  hipLaunchCooperativeKernel((void*)k_main, dim3(GBLK), dim3(GTHR), args, 0, stream);
}

// Round 6
// 1109.771 us; speedup vs baseline: 3.1340x; 1.1684x over previous
//
#include <hip/hip_runtime.h>

#define MDIM 1024
#define H4   4096
#define TKL  10
#define NT   30
#define NWFR 39
#define GBLK 256
#define GTHR 1024
#define AGENT __HIP_MEMORY_SCOPE_AGENT

typedef _Float16 h2v __attribute__((ext_vector_type(2)));
typedef unsigned int uv4 __attribute__((ext_vector_type(4)));
typedef float fv4 __attribute__((ext_vector_type(4)));
union U16 { uv4 u; h2v h[4]; _Float16 f[8]; };

__device__ __forceinline__ float wred(float v) {
#pragma unroll
  for (int o = 32; o; o >>= 1) v += __shfl_xor(v, o, 64);
  return v;
}

__device__ __forceinline__ float dot16(const U16& w, const U16& x, float acc) {
  acc = __builtin_amdgcn_fdot2(w.h[0], x.h[0], acc, false);
  acc = __builtin_amdgcn_fdot2(w.h[1], x.h[1], acc, false);
  acc = __builtin_amdgcn_fdot2(w.h[2], x.h[2], acc, false);
  acc = __builtin_amdgcn_fdot2(w.h[3], x.h[3], acc, false);
  return acc;
}

// write-through 16B store (bypass L1/L2 dirty state -> visible at coherence point)
__device__ __forceinline__ void stg16(const void* p, uv4 v) {
  asm volatile("global_store_dwordx4 %0, %1, off sc0 sc1" :: "v"(p), "v"(v) : "memory");
}

__global__ void k_cvt(const float* __restrict__ in, _Float16* __restrict__ out, int n8) {
  int g = blockIdx.x * blockDim.x + threadIdx.x;
  if (g >= n8) return;
  const float4* p = (const float4*)in;
  float4 a = p[2 * g], b = p[2 * g + 1];
  U16 o;
  o.f[0] = (_Float16)a.x; o.f[1] = (_Float16)a.y;
  o.f[2] = (_Float16)a.z; o.f[3] = (_Float16)a.w;
  o.f[4] = (_Float16)b.x; o.f[5] = (_Float16)b.y;
  o.f[6] = (_Float16)b.z; o.f[7] = (_Float16)b.w;
  ((uv4*)out)[g] = o.u;
}

__global__ void k_xcf(const float* __restrict__ x, float* __restrict__ xcf) {
  int idx = blockIdx.x * blockDim.x + threadIdx.x;
  if (idx >= NT * MDIM) return;
  int i = idx >> 10, m = idx & (MDIM - 1);
  int c = m & 31, s = m >> 5;
  const float* p = x + c * (32 * 360) + s * 360 + i * 12;
  float acc = 0.f;
#pragma unroll
  for (int k = 0; k < 12; ++k) acc += p[k];
  xcf[idx] = acc * (1.0f / 12.0f);
}

__global__ void k_s0(const float* __restrict__ xcf, const float* __restrict__ W,
                     float* __restrict__ S, float* __restrict__ Smir) {
  int wid = (blockIdx.x * blockDim.x + threadIdx.x) >> 6;
  int lane = threadIdx.x & 63;
  if (wid >= NT * MDIM) return;
  int i = wid >> 10, m = wid & (MDIM - 1);
  const float4* wr = (const float4*)(W + (size_t)m * MDIM);
  const float4* xr = (const float4*)(xcf + i * MDIM);
  float acc = 0.f;
#pragma unroll
  for (int k = 0; k < 4; ++k) {
    float4 w = wr[lane + (k << 6)];
    float4 xv = xr[lane + (k << 6)];
    acc += w.x * xv.x + w.y * xv.y + w.z * xv.z + w.w * xv.w;
  }
  acc = wred(acc);
  if (lane == 0) {
    int e = m & ~1;
    float ang = (float)i / powf(10000.0f, (float)e / 512.0f);
    float pe = (m & 1) ? cosf(ang) : sinf(ang);
    float val = acc + pe;
    S[wid] = val;
    Smir[((size_t)i * NT + i) * MDIM + m] = val;
  }
}

// two-level fence-free barrier (proven R4/R5)
__device__ __forceinline__ void gbar(unsigned* bar, unsigned ep) {
  asm volatile("s_waitcnt vmcnt(0)" ::: "memory");
  __syncthreads();
  if (threadIdx.x == 0) {
    unsigned* leaf = bar + ((blockIdx.x & 7) << 5);
    const unsigned prev = __hip_atomic_fetch_add(leaf, 1u, __ATOMIC_RELAXED, AGENT);
    if (prev == ep * 32u - 1u) {
      const unsigned r = __hip_atomic_fetch_add(bar + 256, 1u, __ATOMIC_RELAXED, AGENT);
      if (r == ep * 8u - 1u)
        __hip_atomic_store(bar + 288, ep, __ATOMIC_RELAXED, AGENT);
    }
    while (__hip_atomic_load(bar + 288, __ATOMIC_RELAXED, AGENT) < ep)
      __builtin_amdgcn_s_sleep(2);
  }
  __syncthreads();
}

__global__ __launch_bounds__(GTHR) void k_main(
    const _Float16* __restrict__ Wvh, const _Float16* __restrict__ Woh,
    const _Float16* __restrict__ fc1h, const float* __restrict__ fc1b,
    const _Float16* __restrict__ fc2h, const float* __restrict__ fc2b,
    const float* __restrict__ lng, const float* __restrict__ lnb,
    const float* __restrict__ lzg, const float* __restrict__ lzb,
    float* __restrict__ S, float* __restrict__ ocum,
    float* __restrict__ Smir, float* __restrict__ Omir, float* __restrict__ vmir,
    _Float16* __restrict__ hmir, unsigned* __restrict__ bar) {
  __shared__ __align__(16) _Float16 fc1L[16 * MDIM];   // 32KB, rows b*16..+15
  __shared__ __align__(16) _Float16 fc2L[4 * H4];      // 32KB, rows b*4..+3
  __shared__ __align__(16) _Float16 zxL[2 * TKL * MDIM];  // 40KB: zL | x2L; phase-B hL[5][4096] reuses
  __shared__ __align__(16) _Float16 vstL[3 * MDIM];    // 6KB
  __shared__ __align__(16) float4 stats[TKL];
  __shared__ __align__(16) float vgs[3][16];
  __shared__ __align__(16) _Float16 hgelL2[TKL][16];
  __shared__ float part[4][4][TKL];
  __shared__ __align__(16) float sOut[TKL][4];
  _Float16* zL = zxL;
  _Float16* x2L = zxL + TKL * MDIM;
  _Float16* hL = zxL;  // phase-B reuse (5*4096 = 20480 elems)

  const int tid = threadIdx.x;
  const int lane = tid & 63;
  const int bwave = tid >> 6;
  const int b = blockIdx.x;
  unsigned ep = 0;

  __builtin_amdgcn_fence(__ATOMIC_ACQUIRE, "agent");

  // ---- pin Wv/Wo rows in registers: group g = b + 256r, row (g&63)*16 + bwave ----
  int aR[3], rgR[3];
  bool okR[3];
  U16 wv[3][2], wo[3][2];
#pragma unroll
  for (int r = 0; r < 3; ++r) {
    const int g = b + (r << 8);
    okR[r] = g < 640;
    aR[r] = g >> 6;
    rgR[r] = g & 63;
    if (okR[r]) {
      const size_t off = ((size_t)aR[r] << 20) + ((size_t)((rgR[r] << 4) | bwave) << 10);
      wv[r][0].u = *(const uv4*)(Wvh + off + (lane << 3));
      wv[r][1].u = *(const uv4*)(Wvh + off + 512 + (lane << 3));
      wo[r][0].u = *(const uv4*)(Woh + off + (lane << 3));
      wo[r][1].u = *(const uv4*)(Woh + off + 512 + (lane << 3));
    }
  }
  // ---- persist fc1 (16 rows) and fc2 (4 rows) in LDS ----
  {
    const _Float16* s1 = fc1h + (size_t)b * 16384;
    const _Float16* s2 = fc2h + (size_t)b * 16384;
#pragma unroll
    for (int r = 0; r < 2; ++r) {
      const int s = tid + (r << 10);
      *(uv4*)(fc1L + (s << 3)) = *(const uv4*)(s1 + (s << 3));
      *(uv4*)(fc2L + (s << 3)) = *(const uv4*)(s2 + (s << 3));
    }
  }
  __syncthreads();

  for (int t = 0; t < NWFR; ++t) {
    const int alo = (t - (NT - 1)) > 0 ? (t - (NT - 1)) : 0;
    const int ahi = t < (TKL - 1) ? t : (TKL - 1);
    const int nc = ahi - alo + 1;
    const float* Smirt = Smir + (size_t)t * NT * MDIM;
    const float* Omirt = Omir + (size_t)t * TKL * MDIM;
    bool actR[3];
#pragma unroll
    for (int r = 0; r < 3; ++r)
      actR[r] = okR[r] && aR[r] >= alo && aR[r] <= ahi && (t - aR[r]) != NT - 1;

    // ---- LN stats: one wave per cell, 16 contiguous f32 per lane ----
    if (bwave < nc) {
      const int a = alo + bwave, i = t - a;
      const fv4* sp = (const fv4*)(Smirt + (size_t)i * MDIM + (lane << 4));
      const fv4* op = (const fv4*)(Omirt + (size_t)a * MDIM + (lane << 4));
      fv4 sv[4], tv[4];
#pragma unroll
      for (int k = 0; k < 4; ++k) { sv[k] = sp[k]; tv[k] = sv[k] + op[k]; }
      float s1 = 0.f, t1 = 0.f;
#pragma unroll
      for (int k = 0; k < 4; ++k)
#pragma unroll
        for (int e = 0; e < 4; ++e) { s1 += sv[k][e]; t1 += tv[k][e]; }
      const float mu_s = wred(s1) * (1.0f / MDIM);
      const float mu_t = wred(t1) * (1.0f / MDIM);
      float s2 = 0.f, t2 = 0.f;
#pragma unroll
      for (int k = 0; k < 4; ++k)
#pragma unroll
        for (int e = 0; e < 4; ++e) {
          float d = sv[k][e] - mu_s; s2 += d * d;
          float f = tv[k][e] - mu_t; t2 += f * f;
        }
      const float var_s = wred(s2) * (1.0f / MDIM);
      const float var_t = wred(t2) * (1.0f / MDIM);
      if (!lane)
        stats[bwave] = make_float4(mu_s, rsqrtf(var_s + 1e-5f),
                                   mu_t, rsqrtf(var_t + 1e-5f));
    }
    __syncthreads();

    // ---- elementwise z/x2 into LDS: 8 cells per pass, 128 threads/cell ----
#pragma unroll
    for (int p = 0; p < 2; ++p) {
      const int c = (p << 3) + (tid >> 7);
      if (c < nc) {
        const int a = alo + c, i = t - a;
        const int e = (tid & 127) << 3;
        const float4 st4 = stats[c];
        fv4 sA = *(const fv4*)(Smirt + (size_t)i * MDIM + e);
        fv4 sB = *(const fv4*)(Smirt + (size_t)i * MDIM + e + 4);
        fv4 oA = *(const fv4*)(Omirt + (size_t)a * MDIM + e);
        fv4 oB = *(const fv4*)(Omirt + (size_t)a * MDIM + e + 4);
        fv4 g1A = *(const fv4*)(lng + e), g1B = *(const fv4*)(lng + e + 4);
        fv4 b1A = *(const fv4*)(lnb + e), b1B = *(const fv4*)(lnb + e + 4);
        fv4 g2A = *(const fv4*)(lzg + e), g2B = *(const fv4*)(lzg + e + 4);
        fv4 b2A = *(const fv4*)(lzb + e), b2B = *(const fv4*)(lzb + e + 4);
        U16 zz, xx;
#pragma unroll
        for (int k = 0; k < 4; ++k) {
          zz.f[k] = (_Float16)((sA[k] - st4.x) * st4.y * g1A[k] + b1A[k]);
          zz.f[4 + k] = (_Float16)((sB[k] - st4.x) * st4.y * g1B[k] + b1B[k]);
          const float u0 = sA[k] + oA[k], u1 = sB[k] + oB[k];
          xx.f[k] = (_Float16)((u0 - st4.z) * st4.w * g2A[k] + b2A[k] + u0);
          xx.f[4 + k] = (_Float16)((u1 - st4.z) * st4.w * g2B[k] + b2B[k] + u1);
        }
        *(uv4*)(zL + c * MDIM + e) = zz.u;
        *(uv4*)(x2L + c * MDIM + e) = xx.u;
      }
    }
    __syncthreads();

    // ---- Phase A: Wv from registers; fc1 from LDS ----
#pragma unroll
    for (int r = 0; r < 3; ++r)
      if (actR[r]) {
        const int c = aR[r] - alo;
        U16 z0, z1;
        z0.u = *(const uv4*)(zL + c * MDIM + (lane << 3));
        z1.u = *(const uv4*)(zL + c * MDIM + 512 + (lane << 3));
        float acc = dot16(wv[r][0], z0, 0.f);
        acc = dot16(wv[r][1], z1, acc);
        acc = wred(acc);
        if (!lane) vgs[r][bwave] = acc;
      }
    {
      U16 f0, f1;
      f0.u = *(const uv4*)(fc1L + bwave * MDIM + (lane << 3));
      f1.u = *(const uv4*)(fc1L + bwave * MDIM + 512 + (lane << 3));
      const float bias = fc1b[(b << 4) | bwave];
      float sel = 0.f;
#pragma unroll
      for (int c = 0; c < TKL; ++c)
        if (c < nc) {
          U16 x0, x1;
          x0.u = *(const uv4*)(x2L + c * MDIM + (lane << 3));
          x1.u = *(const uv4*)(x2L + c * MDIM + 512 + (lane << 3));
          float acc = dot16(f0, x0, 0.f);
          acc = dot16(f1, x1, acc);
          acc = wred(acc);
          sel = (lane == c) ? acc : sel;
        }
      const float xg = sel + bias;
      const float ge = 0.5f * xg * (1.0f + erff(xg * 0.70710678118654752f));
      if (lane < nc) hgelL2[lane][bwave] = (_Float16)ge;
    }
    __syncthreads();
    // packed mirror stores: h (16B x2 per cell), v (16B x4 per group)
    if (bwave < nc && lane < 2) {
      uv4 hv = *(const uv4*)(&hgelL2[bwave][lane << 3]);
      stg16(hmir + ((size_t)t * TKL + alo + bwave) * H4 + (b << 4) + (lane << 3), hv);
    }
    if (bwave >= 13 && lane < 4) {
      const int r = bwave - 13;
      if (actR[r]) {
        fv4 vv = *(const fv4*)(&vgs[r][lane << 2]);
        stg16(vmir + ((size_t)t * TKL + aR[r]) * MDIM + (rgR[r] << 4) + (lane << 2),
              __builtin_bit_cast(uv4, vv));
      }
    }
    ++ep; gbar(bar, ep);

    // ---- Phase B: stage v rows + h chunk0 ----
    {
      const int r = tid >> 8, e = (tid & 255) << 2;
      if (r < 3 && actR[r]) {
        fv4 v = *(const fv4*)(vmir + ((size_t)t * TKL + aR[r]) * MDIM + e);
        vstL[(r << 10) + e] = (_Float16)v[0];
        vstL[(r << 10) + e + 1] = (_Float16)v[1];
        vstL[(r << 10) + e + 2] = (_Float16)v[2];
        vstL[(r << 10) + e + 3] = (_Float16)v[3];
      }
    }
#pragma unroll
    for (int rr = 0; rr < 3; ++rr) {
      const int s = tid + (rr << 10);
      if (s < 2560) {
        const int q = s >> 9, idx = (s & 511) << 3;
        if (q < nc)
          *(uv4*)(hL + q * H4 + idx) =
              *(const uv4*)(hmir + ((size_t)t * TKL + alo + q) * H4 + idx);
      }
    }
    __syncthreads();

    // ---- Wo from registers + fc2 chunk0 ----
#pragma unroll
    for (int r = 0; r < 3; ++r)
      if (actR[r]) {
        U16 v0, v1;
        v0.u = *(const uv4*)(vstL + (r << 10) + (lane << 3));
        v1.u = *(const uv4*)(vstL + (r << 10) + 512 + (lane << 3));
        float acc = dot16(wo[r][0], v0, 0.f);
        acc = dot16(wo[r][1], v1, acc);
        acc = wred(acc);
        if (!lane) vgs[r][bwave] = acc;
      }
    const int rl = bwave >> 2, kq = bwave & 3;
    U16 w0, w1;
    w0.u = *(const uv4*)(fc2L + rl * H4 + (kq << 10) + (lane << 3));
    w1.u = *(const uv4*)(fc2L + rl * H4 + (kq << 10) + 512 + (lane << 3));
#pragma unroll
    for (int q = 0; q < 5; ++q)
      if (q < nc) {
        U16 h0, h1;
        h0.u = *(const uv4*)(hL + q * H4 + (kq << 10) + (lane << 3));
        h1.u = *(const uv4*)(hL + q * H4 + (kq << 10) + 512 + (lane << 3));
        float acc = dot16(w0, h0, 0.f);
        acc = dot16(w1, h1, acc);
        acc = wred(acc);
        if (!lane) part[rl][kq][q] = acc;
      }
    __syncthreads();

    // ---- ocum RMW (plain cached, block-exclusive) + Omir write-through; stage h chunk1 ----
    if (bwave >= 13 && lane < 4) {
      const int r = bwave - 13;
      if (actR[r]) {
        const int R = (rgR[r] << 4) + (lane << 2);
        float* po = ocum + aR[r] * MDIM + R;
        fv4 old = *(const fv4*)po;
        fv4 nv = old + *(const fv4*)(&vgs[r][lane << 2]);
        *(fv4*)po = nv;
        stg16(Omir + ((size_t)(t + 1) * TKL + aR[r]) * MDIM + R,
              __builtin_bit_cast(uv4, nv));
      }
    }
#pragma unroll
    for (int rr = 0; rr < 3; ++rr) {
      const int s = tid + (rr << 10);
      if (s < 2560) {
        const int q = s >> 9, idx = (s & 511) << 3;
        const int c = 5 + q;
        if (c < nc)
          *(uv4*)(hL + q * H4 + idx) =
              *(const uv4*)(hmir + ((size_t)t * TKL + alo + c) * H4 + idx);
      }
    }
    __syncthreads();

    // ---- fc2 chunk1 ----
#pragma unroll
    for (int q = 0; q < 5; ++q) {
      const int c = 5 + q;
      if (c < nc) {
        U16 h0, h1;
        h0.u = *(const uv4*)(hL + q * H4 + (kq << 10) + (lane << 3));
        h1.u = *(const uv4*)(hL + q * H4 + (kq << 10) + 512 + (lane << 3));
        float acc = dot16(w0, h0, 0.f);
        acc = dot16(w1, h1, acc);
        acc = wred(acc);
        if (!lane) part[rl][kq][c] = acc;
      }
    }
    __syncthreads();

    // ---- fc2 epilogue: sum quarters, write S (a==9) or Smir(t+1) ----
    if (bwave < nc && lane < 4)
      sOut[bwave][lane] = part[lane][0][bwave] + part[lane][1][bwave] +
                          part[lane][2][bwave] + part[lane][3][bwave] +
                          fc2b[(b << 2) | lane];
    __syncthreads();
    if (bwave < nc && !lane) {
      const int a = alo + bwave, i = t - a;
      fv4 sv = *(const fv4*)(&sOut[bwave][0]);
      if (a == TKL - 1)
        *(fv4*)(S + (size_t)i * MDIM + (b << 2)) = sv;
      else
        stg16(Smir + ((size_t)(t + 1) * NT + i) * MDIM + (b << 2),
              __builtin_bit_cast(uv4, sv));
    }
    ++ep; gbar(bar, ep);
  }
}

extern "C" void kernel_launch(void* const* d_in, const int* in_sizes, int n_in,
                              void* d_out, int out_size, void* d_ws, size_t ws_size,
                              hipStream_t stream) {
  const float* x    = (const float*)d_in[0];
  const float* W    = (const float*)d_in[1];
  const float* Wv   = (const float*)d_in[4];
  const float* Wo   = (const float*)d_in[5];
  const float* lng  = (const float*)d_in[6];
  const float* lnb  = (const float*)d_in[7];
  const float* lzg  = (const float*)d_in[8];
  const float* lzb  = (const float*)d_in[9];
  const float* fc1w = (const float*)d_in[10];
  const float* fc1b = (const float*)d_in[11];
  const float* fc2w = (const float*)d_in[12];
  const float* fc2b = (const float*)d_in[13];
  float* S = (float*)d_out;

  float* xcf  = (float*)d_ws;                 // 30720 f32
  float* ocum = xcf + 30720;                  // 10240 f32
  unsigned* bar = (unsigned*)(ocum + 10240);  // 512 u32
  float* Smir = (float*)(bar + 512);          // 40*30*1024 f32
  float* Omir = Smir + 1228800;               // 40*10*1024 f32
  float* vmir = Omir + 409600;                // 40*10*1024 f32
  _Float16* hmir = (_Float16*)(vmir + 409600);  // 40*10*4096 f16
  _Float16* Wvh  = hmir + 1638400;
  _Float16* Woh  = Wvh + 10485760;
  _Float16* fc1h = Woh + 10485760;
  _Float16* fc2h = fc1h + 4194304;

  hipLaunchKernelGGL(k_cvt, dim3(5120), dim3(256), 0, stream, Wv, Wvh, 1310720);
  hipLaunchKernelGGL(k_cvt, dim3(5120), dim3(256), 0, stream, Wo, Woh, 1310720);
  hipLaunchKernelGGL(k_cvt, dim3(2048), dim3(256), 0, stream, fc1w, fc1h, 524288);
  hipLaunchKernelGGL(k_cvt, dim3(2048), dim3(256), 0, stream, fc2w, fc2h, 524288);
  hipLaunchKernelGGL(k_xcf, dim3((NT * MDIM + 255) / 256), dim3(256), 0, stream, x, xcf);
  hipLaunchKernelGGL(k_s0, dim3(NT * MDIM / 4), dim3(256), 0, stream, xcf, W, S, Smir);
  hipMemsetAsync(ocum, 0, 10240 * sizeof(float), stream);
  hipMemsetAsync(Omir, 0, 409600 * sizeof(float), stream);
  hipMemsetAsync(bar, 0, 2048, stream);

  void* args[] = {(void*)&Wvh, (void*)&Woh, (void*)&fc1h, (void*)&fc1b,
                  (void*)&fc2h, (void*)&fc2b, (void*)&lng, (void*)&lnb,
                  (void*)&lzg, (void*)&lzb, (void*)&S,   (void*)&ocum,
                  (void*)&Smir, (void*)&Omir, (void*)&vmir, (void*)&hmir,
                  (void*)&bar};
  hipLaunchCooperativeKernel((void*)k_main, dim3(GBLK), dim3(GTHR), args, 0, stream);
}